// Round 5
// baseline (958.674 us; speedup 1.0000x reference)
//
#include <hip/hip_runtime.h>

#define NHEADS 8
#define NB 512
#define NN 1000
#define DD 128
#define HH 128
#define SDIM 384              // D*CAT
#define NSPLIT 10             // blocks per batch
#define NSLOT (NSPLIT * 2)    // one partial slot per wave
#define RPW 50                // rows per wave (25 pairs)

// DPP helper: x += lane-permuted x. Pure VALU, no DS pipe.
template <int CTRL>
__device__ __forceinline__ float dpp_add(float x) {
    int y = __builtin_amdgcn_update_dpp(0, __float_as_int(x), CTRL, 0xf, 0xf, true);
    return x + __int_as_float(y);
}
#define DPP_QUAD_XOR1 0xB1   // quad_perm(1,0,3,2)
#define DPP_QUAD_XOR2 0x4E   // quad_perm(2,3,0,1)
#define DPP_HALF_MIRR 0x141  // mirror within 8
#define DPP_ROW_MIRR  0x140  // mirror within 16

__device__ __forceinline__ float dot8(float4 u0, float4 u1, float4 v0, float4 v1) {
    float s = u0.x * v0.x;
    s = fmaf(u0.y, v0.y, s); s = fmaf(u0.z, v0.z, s); s = fmaf(u0.w, v0.w, s);
    s = fmaf(u1.x, v1.x, s); s = fmaf(u1.y, v1.y, s); s = fmaf(u1.z, v1.z, s);
    s = fmaf(u1.w, v1.w, s);
    return s;
}

// ---------------- kernel 0: per-batch qw precompute (coalesced) -------------
__global__ __launch_bounds__(256) void qw_kernel(
    const float* __restrict__ state_t,   // [B][384]
    const float* __restrict__ Wq,        // [128][384]
    const float* __restrict__ Wk,        // [128][128]
    float* __restrict__ qw)              // [B][8][128]
{
    const int b = blockIdx.x;
    const int t = threadIdx.x;
    const int lane = t & 63;
    const int w = t >> 6;

    __shared__ float s_q[HH];

    float st[6];
    #pragma unroll
    for (int j = 0; j < 6; ++j) st[j] = state_t[(size_t)b * SDIM + j * 64 + lane];

    for (int it = 0; it < 16; ++it) {
        const int r0 = w * 32 + it * 2;
        const float* w0 = Wq + (size_t)r0 * SDIM;
        const float* w1 = w0 + SDIM;
        float p0 = 0.f, p1 = 0.f;
        #pragma unroll
        for (int j = 0; j < 6; ++j) {
            p0 = fmaf(w0[j * 64 + lane], st[j], p0);
            p1 = fmaf(w1[j * 64 + lane], st[j], p1);
        }
        #pragma unroll
        for (int off = 32; off >= 1; off >>= 1) {
            p0 += __shfl_xor(p0, off, 64);
            p1 += __shfl_xor(p1, off, 64);
        }
        if (lane == 0) { s_q[r0] = p0; s_q[r0 + 1] = p1; }
    }
    __syncthreads();

    {
        const int d  = t & 127;
        const int h0 = (t >> 7) * 4;
        const float sc = 0.0625f * 1.4426950408889634f;  // (1/hd) * log2(e)
        for (int hh = 0; hh < 4; ++hh) {
            const int h = h0 + hh;
            float a = 0.f;
            #pragma unroll
            for (int j = 0; j < 16; ++j)
                a = fmaf(s_q[h * 16 + j], Wk[(size_t)(h * 16 + j) * DD + d], a);
            qw[(size_t)b * NHEADS * DD + h * DD + d] = a * sc;
        }
    }
}

// ---------------- kernel 1: fused partial + last-block combine --------------
// Block = (split s, batch b), 128 threads = 2 waves; wave = 4 groups of 16
// lanes; group g = head pair (2g,2g+1); lane j owns floats [j*8, j*8+8).
// Rows processed in pairs with depth-2 register prefetch (pipeline A/B).
// Last block per batch (atomic counter) performs combine + Wv/Wfc projection.
__global__ __launch_bounds__(128, 5) void attn_fused_kernel(
    const float* __restrict__ context,   // [B][N][128]
    const int*   __restrict__ mask,      // [B][N]
    const float* __restrict__ qw,        // [B][8][128] (pre-scaled)
    const float* __restrict__ Wv,        // [128][128]
    const float* __restrict__ Wfc,       // [128][128]
    float* __restrict__ part_acc,        // [B][NSLOT][8][128]
    float* __restrict__ part_den,        // [B][NSLOT][8]
    int*   __restrict__ cnt,             // [B], zeroed before launch
    float* __restrict__ out)             // [B][128]
{
    const int s = blockIdx.x;
    const int b = blockIdx.y;
    const int w = threadIdx.x >> 6;
    const int lane = threadIdx.x & 63;
    const int g = lane >> 4;     // head pair
    const int j = lane & 15;     // d-slice

    // qw slices for heads 2g, 2g+1 (16 regs)
    const float* qwb = qw + (size_t)b * NHEADS * DD + j * 8;
    const float4 qa0 = *reinterpret_cast<const float4*>(qwb + (2 * g) * DD);
    const float4 qa1 = *reinterpret_cast<const float4*>(qwb + (2 * g) * DD + 4);
    const float4 qb0 = *reinterpret_cast<const float4*>(qwb + (2 * g + 1) * DD);
    const float4 qb1 = *reinterpret_cast<const float4*>(qwb + (2 * g + 1) * DD + 4);

    float4 A0 = make_float4(0.f, 0.f, 0.f, 0.f), A1 = A0;  // acc head 2g
    float4 B0 = A0, B1 = A0;                                // acc head 2g+1
    float den0 = 0.f, den1 = 0.f;

    const int row0 = s * (2 * RPW) + w * RPW;
    const float* cp = context + ((size_t)b * NN + row0) * DD + j * 8;
    const int*   mp = mask + (size_t)b * NN + row0;

    // pipeline buffers: X = pair k (even), Y = pair k+1
    float4 x00, x01, x10, x11; int mx0, mx1;
    float4 y00, y01, y10, y11; int my0, my1;
    {
        const float* p0 = cp;
        x00 = *reinterpret_cast<const float4*>(p0);
        x01 = *reinterpret_cast<const float4*>(p0 + 4);
        x10 = *reinterpret_cast<const float4*>(p0 + DD);
        x11 = *reinterpret_cast<const float4*>(p0 + DD + 4);
        mx0 = mp[0]; mx1 = mp[1];
        const float* p1 = cp + 2 * DD;
        y00 = *reinterpret_cast<const float4*>(p1);
        y01 = *reinterpret_cast<const float4*>(p1 + 4);
        y10 = *reinterpret_cast<const float4*>(p1 + DD);
        y11 = *reinterpret_cast<const float4*>(p1 + DD + 4);
        my0 = mp[2]; my1 = mp[3];
    }

    auto proc = [&](float4& c00, float4& c01, float4& c10, float4& c11,
                    int& m0, int& m1, int itn) {
        // scores: 2 rows x 2 heads, 4 independent chains
        float sa0 = dot8(c00, c01, qa0, qa1);   // row even, head 2g
        float sb0 = dot8(c00, c01, qb0, qb1);   // row even, head 2g+1
        float sa1 = dot8(c10, c11, qa0, qa1);   // row odd,  head 2g
        float sb1 = dot8(c10, c11, qb0, qb1);   // row odd,  head 2g+1

        sa0 = dpp_add<DPP_QUAD_XOR1>(sa0); sb0 = dpp_add<DPP_QUAD_XOR1>(sb0);
        sa1 = dpp_add<DPP_QUAD_XOR1>(sa1); sb1 = dpp_add<DPP_QUAD_XOR1>(sb1);
        sa0 = dpp_add<DPP_QUAD_XOR2>(sa0); sb0 = dpp_add<DPP_QUAD_XOR2>(sb0);
        sa1 = dpp_add<DPP_QUAD_XOR2>(sa1); sb1 = dpp_add<DPP_QUAD_XOR2>(sb1);
        sa0 = dpp_add<DPP_HALF_MIRR>(sa0); sb0 = dpp_add<DPP_HALF_MIRR>(sb0);
        sa1 = dpp_add<DPP_HALF_MIRR>(sa1); sb1 = dpp_add<DPP_HALF_MIRR>(sb1);
        sa0 = dpp_add<DPP_ROW_MIRR>(sa0);  sb0 = dpp_add<DPP_ROW_MIRR>(sb0);
        sa1 = dpp_add<DPP_ROW_MIRR>(sa1);  sb1 = dpp_add<DPP_ROW_MIRR>(sb1);

        const float pa0 = m0 ? 0.f : exp2f(sa0);
        const float pb0 = m0 ? 0.f : exp2f(sb0);
        const float pa1 = m1 ? 0.f : exp2f(sa1);
        const float pb1 = m1 ? 0.f : exp2f(sb1);
        den0 += pa0 + pa1;
        den1 += pb0 + pb1;

        A0.x = fmaf(pa0, c00.x, fmaf(pa1, c10.x, A0.x));
        A0.y = fmaf(pa0, c00.y, fmaf(pa1, c10.y, A0.y));
        A0.z = fmaf(pa0, c00.z, fmaf(pa1, c10.z, A0.z));
        A0.w = fmaf(pa0, c00.w, fmaf(pa1, c10.w, A0.w));
        A1.x = fmaf(pa0, c01.x, fmaf(pa1, c11.x, A1.x));
        A1.y = fmaf(pa0, c01.y, fmaf(pa1, c11.y, A1.y));
        A1.z = fmaf(pa0, c01.z, fmaf(pa1, c11.z, A1.z));
        A1.w = fmaf(pa0, c01.w, fmaf(pa1, c11.w, A1.w));
        B0.x = fmaf(pb0, c00.x, fmaf(pb1, c10.x, B0.x));
        B0.y = fmaf(pb0, c00.y, fmaf(pb1, c10.y, B0.y));
        B0.z = fmaf(pb0, c00.z, fmaf(pb1, c10.z, B0.z));
        B0.w = fmaf(pb0, c00.w, fmaf(pb1, c10.w, B0.w));
        B1.x = fmaf(pb0, c01.x, fmaf(pb1, c11.x, B1.x));
        B1.y = fmaf(pb0, c01.y, fmaf(pb1, c11.y, B1.y));
        B1.z = fmaf(pb0, c01.z, fmaf(pb1, c11.z, B1.z));
        B1.w = fmaf(pb0, c01.w, fmaf(pb1, c11.w, B1.w));

        // prefetch pair itn+2 (clamped; harmless reload at the tail)
        int pr = itn + 2;
        if (pr > RPW / 2 - 1) pr = RPW / 2 - 1;
        const float* np = cp + (size_t)(2 * pr) * DD;
        c00 = *reinterpret_cast<const float4*>(np);
        c01 = *reinterpret_cast<const float4*>(np + 4);
        c10 = *reinterpret_cast<const float4*>(np + DD);
        c11 = *reinterpret_cast<const float4*>(np + DD + 4);
        m0 = mp[2 * pr]; m1 = mp[2 * pr + 1];
    };

    // 25 pairs: 12 double iterations + 1 final
    for (int it = 0; it < 12; ++it) {
        proc(x00, x01, x10, x11, mx0, mx1, 2 * it);
        proc(y00, y01, y10, y11, my0, my1, 2 * it + 1);
    }
    proc(x00, x01, x10, x11, mx0, mx1, 24);

    // ---- write this wave's partial slot (no LDS, no barrier) ----
    const int slot = s * 2 + w;
    float* pa = part_acc + (((size_t)b * NSLOT + slot) * NHEADS) * DD + j * 8;
    *reinterpret_cast<float4*>(pa + (2 * g) * DD)         = A0;
    *reinterpret_cast<float4*>(pa + (2 * g) * DD + 4)     = A1;
    *reinterpret_cast<float4*>(pa + (2 * g + 1) * DD)     = B0;
    *reinterpret_cast<float4*>(pa + (2 * g + 1) * DD + 4) = B1;
    if (j == 0) {
        float* pd = part_den + ((size_t)b * NSLOT + slot) * NHEADS;
        pd[2 * g]     = den0;
        pd[2 * g + 1] = den1;
    }

    // ---- last block per batch does the combine ----
    __shared__ int s_last;
    __threadfence();                     // release partials (device scope)
    __syncthreads();
    if (threadIdx.x == 0)
        s_last = (atomicAdd(&cnt[b], 1) == NSPLIT - 1) ? 1 : 0;
    __syncthreads();
    if (!s_last) return;
    __threadfence();                     // acquire other blocks' partials

    __shared__ float s_dn[NHEADS];
    __shared__ float s_ca[NHEADS][132];
    __shared__ float s_o2[HH];
    const int t = threadIdx.x;           // 128 threads

    if (t < NHEADS) {
        float dn = 0.f;
        #pragma unroll
        for (int sp = 0; sp < NSLOT; ++sp)
            dn += part_den[((size_t)b * NSLOT + sp) * NHEADS + t];
        s_dn[t] = dn;
    }
    __syncthreads();

    {
        const int d = t;
        #pragma unroll
        for (int h = 0; h < NHEADS; ++h) {
            float a = 0.f;
            #pragma unroll
            for (int sp = 0; sp < NSLOT; ++sp)
                a += part_acc[(((size_t)b * NSLOT + sp) * NHEADS + h) * DD + d];
            s_ca[h][d] = a / s_dn[h];
        }
    }
    __syncthreads();

    {
        const int h = t >> 4;
        const float* wvr = Wv + (size_t)t * DD;
        float a = 0.f;
        #pragma unroll 4
        for (int d = 0; d < DD; ++d) a = fmaf(s_ca[h][d], wvr[d], a);
        s_o2[t] = a;
    }
    __syncthreads();

    {
        const float* wfc = Wfc + (size_t)t * DD;
        float a = 0.f;
        #pragma unroll 4
        for (int k = 0; k < DD; ++k) a = fmaf(s_o2[k], wfc[k], a);
        out[(size_t)b * HH + t] = a;
    }
}

extern "C" void kernel_launch(void* const* d_in, const int* in_sizes, int n_in,
                              void* d_out, int out_size, void* d_ws, size_t ws_size,
                              hipStream_t stream) {
    const float* state_t = (const float*)d_in[0];
    const float* context = (const float*)d_in[1];
    const int*   mask    = (const int*)d_in[2];
    const float* Wq      = (const float*)d_in[3];
    const float* Wk      = (const float*)d_in[4];
    const float* Wv      = (const float*)d_in[5];
    const float* Wfc     = (const float*)d_in[6];
    float* out = (float*)d_out;

    float* qw       = (float*)d_ws;                                  // 2 MB
    float* part_acc = qw + (size_t)NB * NHEADS * DD;                 // 42 MB
    float* part_den = part_acc + (size_t)NB * NSLOT * NHEADS * DD;   // 0.3 MB
    int*   cnt      = (int*)(part_den + (size_t)NB * NSLOT * NHEADS);

    hipMemsetAsync(cnt, 0, NB * sizeof(int), stream);
    qw_kernel<<<dim3(NB), dim3(256), 0, stream>>>(state_t, Wq, Wk, qw);
    attn_fused_kernel<<<dim3(NSPLIT, NB), dim3(128), 0, stream>>>(
        context, mask, qw, Wv, Wfc, part_acc, part_den, cnt, out);
}